// Round 3
// baseline (55.317 us; speedup 1.0000x reference)
//
#include <hip/hip_runtime.h>

// Problem constants (match setup_inputs: BS=4, H=W=64, NG=2, NP=192, step=20)
#define HW    4096
#define STEP  20
#define NV    204          // HW / STEP
#define NPNT  192
#define NGRP  2
#define BSZ   4
#define SCORING_WEIGHT 0.01f
#define FXSCALE 1099511627776.0   // 2^40 fixed-point scale

// Fused kernel: one block per (b, g, n), 192 threads (thread t owns GT point t).
// Identity: R orthonormal =>  |T_t - (R G_p + pt)| = |R^T (T_t - pt) - G_p|,
// so the hot loop is min_p |V - G_p|^2 with G read straight from global
// (block-uniform addresses -> scalar/constant-cache loads, float4-wide).
// Cross-block reduction: fixed-point uint64 atomicAdd (order-independent =>
// bit-exact deterministic) + last-block-writes-out.
__global__ __launch_bounds__(192) void k_fused(
    const float* __restrict__ pred_r,   // (BS,4,H,W)
    const float* __restrict__ pred_t,   // (BS,3,H,W)
    const float* __restrict__ pred_s,   // (BS,1,H,W)
    const float* __restrict__ gt_r,     // (BS,3,3)
    const float* __restrict__ gt_t,     // (BS,3)
    const float* __restrict__ grps,     // (NG,3,NP)
    unsigned long long* __restrict__ acc,   // ws: fixed-point accumulator
    unsigned int* __restrict__ counter,     // ws: completion counter
    float* __restrict__ out)
{
    const int blk = blockIdx.x;
    const int n   = blk % NV;
    const int g   = (blk / NV) % NGRP;
    const int b   = blk / (NV * NGRP);
    const int pix = n * STEP;
    const int tid = threadIdx.x;

    // --- quaternion -> rotation (normalized per-pixel); all uniform loads ---
    float q0 = pred_r[(b * 4 + 0) * HW + pix];
    float q1 = pred_r[(b * 4 + 1) * HW + pix];
    float q2 = pred_r[(b * 4 + 2) * HW + pix];
    float q3 = pred_r[(b * 4 + 3) * HW + pix];
    {
        float inv = 1.0f / sqrtf(q0 * q0 + q1 * q1 + q2 * q2 + q3 * q3);
        q0 *= inv; q1 *= inv; q2 *= inv; q3 *= inv;
    }
    const float R00 = 1.f - 2.f * (q2 * q2 + q3 * q3);
    const float R01 = 2.f * q1 * q2 - 2.f * q0 * q3;
    const float R02 = 2.f * q0 * q2 + 2.f * q1 * q3;
    const float R10 = 2.f * q1 * q2 + 2.f * q3 * q0;
    const float R11 = 1.f - 2.f * (q1 * q1 + q3 * q3);
    const float R12 = -2.f * q0 * q1 + 2.f * q2 * q3;
    const float R20 = -2.f * q0 * q2 + 2.f * q1 * q3;
    const float R21 = 2.f * q0 * q1 + 2.f * q2 * q3;
    const float R22 = 1.f - 2.f * (q1 * q1 + q2 * q2);

    const float pt0 = pred_t[(b * 3 + 0) * HW + pix];
    const float pt1 = pred_t[(b * 3 + 1) * HW + pix];
    const float pt2 = pred_t[(b * 3 + 2) * HW + pix];

    const float* __restrict__ G0 = grps + g * 3 * NPNT;
    const float* __restrict__ G1 = G0 + NPNT;
    const float* __restrict__ G2 = G0 + 2 * NPNT;

    // --- T point t = tid, into group frame: V = R^T (T - pt) ---
    float V0, V1, V2;
    {
        const float a0 = G0[tid];   // per-lane coalesced
        const float a1 = G1[tid];
        const float a2 = G2[tid];
        const float* Rb = gt_r + b * 9;   // uniform -> scalar loads
        const float* tb = gt_t + b * 3;
        const float T0 = Rb[0] * a0 + Rb[1] * a1 + Rb[2] * a2 + tb[0];
        const float T1 = Rb[3] * a0 + Rb[4] * a1 + Rb[5] * a2 + tb[1];
        const float T2 = Rb[6] * a0 + Rb[7] * a1 + Rb[8] * a2 + tb[2];
        const float u0 = T0 - pt0;
        const float u1 = T1 - pt1;
        const float u2 = T2 - pt2;
        V0 = R00 * u0 + R10 * u1 + R20 * u2;   // R^T rows = R columns
        V1 = R01 * u0 + R11 * u1 + R21 * u2;
        V2 = R02 * u0 + R12 * u1 + R22 * u2;
    }

    // --- min over p of |V - G_p|^2 ; float4-wide uniform loads ---
    const float4* __restrict__ G0v = reinterpret_cast<const float4*>(G0);
    const float4* __restrict__ G1v = reinterpret_cast<const float4*>(G1);
    const float4* __restrict__ G2v = reinterpret_cast<const float4*>(G2);
    float mm0 = 3.4e38f, mm1 = 3.4e38f, mm2 = 3.4e38f, mm3 = 3.4e38f;
#pragma unroll 4
    for (int p4 = 0; p4 < NPNT / 4; ++p4) {
        const float4 x = G0v[p4];
        const float4 y = G1v[p4];
        const float4 z = G2v[p4];
        {
            const float dx = V0 - x.x, dy = V1 - y.x, dz = V2 - z.x;
            mm0 = fminf(mm0, dx * dx + dy * dy + dz * dz);
        }
        {
            const float dx = V0 - x.y, dy = V1 - y.y, dz = V2 - z.y;
            mm1 = fminf(mm1, dx * dx + dy * dy + dz * dz);
        }
        {
            const float dx = V0 - x.z, dy = V1 - y.z, dz = V2 - z.z;
            mm2 = fminf(mm2, dx * dx + dy * dy + dz * dz);
        }
        {
            const float dx = V0 - x.w, dy = V1 - y.w, dz = V2 - z.w;
            mm3 = fminf(mm3, dx * dx + dy * dy + dz * dz);
        }
    }
    const float m = fminf(fminf(mm0, mm1), fminf(mm2, mm3));
    const float dist = sqrtf(fmaxf(m, 1e-12f));

    // --- wave shuffle-reduce (64 lanes), then combine 3 waves via LDS ---
    float s = dist;
    for (int off = 32; off > 0; off >>= 1) s += __shfl_down(s, off);
    __shared__ float wsum[3];
    const int wid  = tid >> 6;
    const int lane = tid & 63;
    if (lane == 0) wsum[wid] = s;
    __syncthreads();

    if (tid == 0) {
        const float dist_sum = wsum[0] + wsum[1] + wsum[2];
        const float ps = pred_s[b * HW + pix];
        float term = dist_sum * ps * (1.0f / (NGRP * NPNT));
        if (g == 0) term += -SCORING_WEIGHT * logf(ps);   // term >= 0 always
        const unsigned long long fx =
            (unsigned long long)((double)term * FXSCALE + 0.5);
        atomicAdd(acc, fx);
        __threadfence();
        const unsigned int prev = atomicAdd(counter, 1u);
        if (prev == (unsigned int)(BSZ * NGRP * NV - 1)) {
            const unsigned long long tot = atomicAdd(acc, 0ULL);  // coherent read
            out[0] = (float)((double)tot / FXSCALE / (double)(BSZ * NV));
        }
    }
}

extern "C" void kernel_launch(void* const* d_in, const int* in_sizes, int n_in,
                              void* d_out, int out_size, void* d_ws, size_t ws_size,
                              hipStream_t stream) {
    const float* pred_r = (const float*)d_in[0];
    const float* pred_t = (const float*)d_in[1];
    const float* pred_s = (const float*)d_in[2];
    const float* gt_r   = (const float*)d_in[3];
    const float* gt_t   = (const float*)d_in[4];
    const float* grps   = (const float*)d_in[5];
    // d_in[6] = mask (all-ones, unused by reference math), d_in[7] = cls_ids
    // (unused), d_in[8] = step (fixed at 20; baked into STEP/NV)
    float* out = (float*)d_out;
    unsigned long long* acc = (unsigned long long*)d_ws;
    unsigned int* counter   = (unsigned int*)((char*)d_ws + 8);

    // zero the 16-byte accumulator block every call (graph-capturable node)
    hipMemsetAsync(d_ws, 0, 16, stream);
    k_fused<<<BSZ * NGRP * NV, 192, 0, stream>>>(
        pred_r, pred_t, pred_s, gt_r, gt_t, grps, acc, counter, out);
}

// Round 4
// 26.129 us; speedup vs baseline: 2.1170x; 2.1170x over previous
//
#include <hip/hip_runtime.h>

// Problem constants (match setup_inputs: BS=4, H=W=64, NG=2, NP=192, step=20)
#define HW    4096
#define STEP  20
#define NV    204          // HW / STEP
#define NPNT  192
#define NGRP  2
#define BSZ   4
#define SCORING_WEIGHT 0.01f

// One block per (b, n): 192 threads, thread t owns GT point t for BOTH groups.
// Identity: R orthonormal =>  |T_t - (R G_p + pt)| = |R^T (T_t - pt) - G_p|.
// Both group clouds staged once into LDS (4.6 KB); hot loop reads them as
// uniform-address ds_read_b128 broadcasts (conflict-free) -> VALU-bound.
// Block writes the COMPLETE per-(b,n) loss term (ps weighting + log term);
// no atomics, no fences — kernel boundary provides visibility.
__global__ __launch_bounds__(192) void k_dist(
    const float* __restrict__ pred_r,   // (BS,4,H,W)
    const float* __restrict__ pred_t,   // (BS,3,H,W)
    const float* __restrict__ pred_s,   // (BS,1,H,W)
    const float* __restrict__ gt_r,     // (BS,3,3)
    const float* __restrict__ gt_t,     // (BS,3)
    const float* __restrict__ grps,     // (NG,3,NP)
    float* __restrict__ partial)        // (BS*NV) complete per-(b,n) terms
{
    __shared__ float4 sG[NGRP][3][NPNT / 4];   // both group clouds
    __shared__ float wsum[2][3];

    const int blk = blockIdx.x;
    const int n   = blk % NV;
    const int b   = blk / NV;
    const int pix = n * STEP;
    const int tid = threadIdx.x;

    // --- stage G into LDS (coalesced), keep own column for the T transform ---
    float a[NGRP][3];
#pragma unroll
    for (int g = 0; g < NGRP; ++g)
#pragma unroll
        for (int r = 0; r < 3; ++r) {
            const float v = grps[(g * 3 + r) * NPNT + tid];
            a[g][r] = v;
            reinterpret_cast<float*>(&sG[g][r][0])[tid] = v;
        }

    // --- quaternion -> rotation (uniform loads) ---
    float q0 = pred_r[(b * 4 + 0) * HW + pix];
    float q1 = pred_r[(b * 4 + 1) * HW + pix];
    float q2 = pred_r[(b * 4 + 2) * HW + pix];
    float q3 = pred_r[(b * 4 + 3) * HW + pix];
    {
        float inv = 1.0f / sqrtf(q0 * q0 + q1 * q1 + q2 * q2 + q3 * q3);
        q0 *= inv; q1 *= inv; q2 *= inv; q3 *= inv;
    }
    const float R00 = 1.f - 2.f * (q2 * q2 + q3 * q3);
    const float R01 = 2.f * q1 * q2 - 2.f * q0 * q3;
    const float R02 = 2.f * q0 * q2 + 2.f * q1 * q3;
    const float R10 = 2.f * q1 * q2 + 2.f * q3 * q0;
    const float R11 = 1.f - 2.f * (q1 * q1 + q3 * q3);
    const float R12 = -2.f * q0 * q1 + 2.f * q2 * q3;
    const float R20 = -2.f * q0 * q2 + 2.f * q1 * q3;
    const float R21 = 2.f * q0 * q1 + 2.f * q2 * q3;
    const float R22 = 1.f - 2.f * (q1 * q1 + q2 * q2);

    const float pt0 = pred_t[(b * 3 + 0) * HW + pix];
    const float pt1 = pred_t[(b * 3 + 1) * HW + pix];
    const float pt2 = pred_t[(b * 3 + 2) * HW + pix];

    // --- per-lane T point -> group frame: V = R^T (gt_r a + gt_t - pt) ---
    const float* Rb = gt_r + b * 9;   // uniform -> scalar loads
    const float* tb = gt_t + b * 3;
    float V[NGRP][3];
#pragma unroll
    for (int g = 0; g < NGRP; ++g) {
        const float T0 = Rb[0] * a[g][0] + Rb[1] * a[g][1] + Rb[2] * a[g][2] + tb[0];
        const float T1 = Rb[3] * a[g][0] + Rb[4] * a[g][1] + Rb[5] * a[g][2] + tb[1];
        const float T2 = Rb[6] * a[g][0] + Rb[7] * a[g][1] + Rb[8] * a[g][2] + tb[2];
        const float u0 = T0 - pt0;
        const float u1 = T1 - pt1;
        const float u2 = T2 - pt2;
        V[g][0] = R00 * u0 + R10 * u1 + R20 * u2;   // R^T rows = R columns
        V[g][1] = R01 * u0 + R11 * u1 + R21 * u2;
        V[g][2] = R02 * u0 + R12 * u1 + R22 * u2;
    }
    __syncthreads();

    // --- hot loop: min_p |V - G_p|^2, both groups; broadcast b128 reads ---
    float m0a = 3.4e38f, m0b = 3.4e38f, m0c = 3.4e38f, m0d = 3.4e38f;
    float m1a = 3.4e38f, m1b = 3.4e38f, m1c = 3.4e38f, m1d = 3.4e38f;
#pragma unroll 4
    for (int p4 = 0; p4 < NPNT / 4; ++p4) {
        {
            const float4 x = sG[0][0][p4], y = sG[0][1][p4], z = sG[0][2][p4];
            float dx, dy, dz;
            dx = V[0][0] - x.x; dy = V[0][1] - y.x; dz = V[0][2] - z.x;
            m0a = fminf(m0a, dx * dx + dy * dy + dz * dz);
            dx = V[0][0] - x.y; dy = V[0][1] - y.y; dz = V[0][2] - z.y;
            m0b = fminf(m0b, dx * dx + dy * dy + dz * dz);
            dx = V[0][0] - x.z; dy = V[0][1] - y.z; dz = V[0][2] - z.z;
            m0c = fminf(m0c, dx * dx + dy * dy + dz * dz);
            dx = V[0][0] - x.w; dy = V[0][1] - y.w; dz = V[0][2] - z.w;
            m0d = fminf(m0d, dx * dx + dy * dy + dz * dz);
        }
        {
            const float4 x = sG[1][0][p4], y = sG[1][1][p4], z = sG[1][2][p4];
            float dx, dy, dz;
            dx = V[1][0] - x.x; dy = V[1][1] - y.x; dz = V[1][2] - z.x;
            m1a = fminf(m1a, dx * dx + dy * dy + dz * dz);
            dx = V[1][0] - x.y; dy = V[1][1] - y.y; dz = V[1][2] - z.y;
            m1b = fminf(m1b, dx * dx + dy * dy + dz * dz);
            dx = V[1][0] - x.z; dy = V[1][1] - y.z; dz = V[1][2] - z.z;
            m1c = fminf(m1c, dx * dx + dy * dy + dz * dz);
            dx = V[1][0] - x.w; dy = V[1][1] - y.w; dz = V[1][2] - z.w;
            m1d = fminf(m1d, dx * dx + dy * dy + dz * dz);
        }
    }
    const float d0 = sqrtf(fmaxf(fminf(fminf(m0a, m0b), fminf(m0c, m0d)), 1e-12f));
    const float d1 = sqrtf(fmaxf(fminf(fminf(m1a, m1b), fminf(m1c, m1d)), 1e-12f));

    // --- wave shuffle reduce both sums, combine 3 waves via LDS ---
    float s0 = d0, s1 = d1;
    for (int off = 32; off > 0; off >>= 1) {
        s0 += __shfl_down(s0, off);
        s1 += __shfl_down(s1, off);
    }
    const int wid  = tid >> 6;
    const int lane = tid & 63;
    if (lane == 0) { wsum[0][wid] = s0; wsum[1][wid] = s1; }
    __syncthreads();

    if (tid == 0) {
        const float ds = wsum[0][0] + wsum[0][1] + wsum[0][2]
                       + wsum[1][0] + wsum[1][1] + wsum[1][2];
        const float ps = pred_s[b * HW + pix];
        partial[blk] = ps * ds * (1.0f / (NGRP * NPNT))
                     - SCORING_WEIGHT * logf(ps);
    }
}

// Single-block deterministic final sum of 816 complete terms.
__global__ __launch_bounds__(256) void k_reduce(
    const float* __restrict__ partial,   // (BS*NV)
    float* __restrict__ out)
{
    __shared__ float red[256];
    const int tid = threadIdx.x;
    float acc = 0.f;
    for (int k = tid; k < BSZ * NV; k += 256) acc += partial[k];
    red[tid] = acc;
    __syncthreads();
    for (int s = 128; s > 0; s >>= 1) {
        if (tid < s) red[tid] += red[tid + s];
        __syncthreads();
    }
    if (tid == 0) out[0] = red[0] * (1.0f / (BSZ * NV));
}

extern "C" void kernel_launch(void* const* d_in, const int* in_sizes, int n_in,
                              void* d_out, int out_size, void* d_ws, size_t ws_size,
                              hipStream_t stream) {
    const float* pred_r = (const float*)d_in[0];
    const float* pred_t = (const float*)d_in[1];
    const float* pred_s = (const float*)d_in[2];
    const float* gt_r   = (const float*)d_in[3];
    const float* gt_t   = (const float*)d_in[4];
    const float* grps   = (const float*)d_in[5];
    // d_in[6] = mask (all-ones, unused), d_in[7] = cls_ids (unused),
    // d_in[8] = step (fixed at 20; baked into STEP/NV)
    float* out     = (float*)d_out;
    float* partial = (float*)d_ws;   // BS*NV floats = 3264 B

    k_dist<<<BSZ * NV, 192, 0, stream>>>(
        pred_r, pred_t, pred_s, gt_r, gt_t, grps, partial);
    k_reduce<<<1, 256, 0, stream>>>(partial, out);
}